// Round 1
// baseline (3055.357 us; speedup 1.0000x reference)
//
#include <hip/hip_runtime.h>
#include <hip/hip_bf16.h>

// EnhancedOFTLinearLayer: out = x @ (W @ blockdiag(cayley(R)))^T + bias
//   cayley(A): S = 0.5(A - A^T); Q = (I - S) @ inv((1+1e-6)I + S)
// Pipeline:
//   1) build M = (1+1e-6)I + S                        (f32, ws)
//   2) power iteration -> sigma_max(S)^2 -> alpha     (per block)
//   3) X0 = alpha * M^T ; 10x bf16 Newton (X<-X(2I-MX)) ; 1x split-precision
//      polish ; Q = (2+1e-6)X - M X  (fused epilogue)
//   4) tw = W @ blockdiag(Q)  (bf16 out)
//   5) x -> bf16 ; out = x_bf @ tw^T + bias  (m97-style 128x128 MFMA GEMM)

typedef unsigned short u16;
typedef __attribute__((ext_vector_type(8))) __bf16 bf16x8;
typedef __attribute__((ext_vector_type(4))) float f32x4;
typedef __attribute__((ext_vector_type(8))) unsigned short u16x8;

#define C0   1.000001f   /* 1 + 1e-6 */
#define C1Q  2.000001f   /* 1 + C0   */

__device__ __forceinline__ u16 f2bf(float x) {
  union { float f; unsigned u; } v; v.f = x;
  return (u16)((v.u + 0x7fffu + ((v.u >> 16) & 1u)) >> 16);
}
__device__ __forceinline__ float bf2f(u16 h) {
  union { float f; unsigned u; } v; v.u = ((unsigned)h) << 16; return v.f;
}

// ---------------- 1) M = (1+1e-6)I + 0.5(R - R^T) ----------------
__global__ __launch_bounds__(256) void k_build_M(const float* __restrict__ R,
                                                 float* __restrict__ M) {
  int idx = blockIdx.x * 256 + threadIdx.x;          // 8*512*512 total
  int n = idx >> 18, r = (idx >> 9) & 511, c = idx & 511;
  float a  = R[idx];
  float at = R[(n << 18) | (c << 9) | r];
  float s  = 0.5f * (a - at);
  M[idx] = s + (r == c ? C0 : 0.0f);
}

// ---------------- 2) power iteration -> alpha[n] ----------------
__global__ __launch_bounds__(256) void k_power_alpha(const float* __restrict__ M,
                                                     float* __restrict__ alpha) {
  __shared__ float v[512], t[512], red[4];
  const int n = blockIdx.x, tid = threadIdx.x;
  const float* Mb = M + (size_t)n * 262144;
  for (int i = tid; i < 512; i += 256) {
    unsigned h = (unsigned)(i * 1103515245u + 12345u + (unsigned)n * 2654435761u);
    v[i] = (float)(h & 0xffffu) * (1.0f / 65536.0f) - 0.5f;
  }
  __syncthreads();
  float lam = 1.0f;
  for (int it = 0; it < 30; ++it) {
    for (int r = tid; r < 512; r += 256) {           // t = S v = M v - c0 v
      const float* row = Mb + r * 512;
      float acc = 0.f;
      for (int c = 0; c < 512; ++c) acc += row[c] * v[c];
      t[r] = acc - C0 * v[r];
    }
    __syncthreads();
    for (int r = tid; r < 512; r += 256) {           // v = -S t = c0 t - M t
      const float* row = Mb + r * 512;
      float acc = 0.f;
      for (int c = 0; c < 512; ++c) acc += row[c] * t[c];
      v[r] = C0 * t[r] - acc;
    }
    __syncthreads();
    float ps = 0.f;
    for (int r = tid; r < 512; r += 256) ps += v[r] * v[r];
    for (int off = 32; off > 0; off >>= 1) ps += __shfl_down(ps, off, 64);
    if ((tid & 63) == 0) red[tid >> 6] = ps;
    __syncthreads();
    lam = sqrtf(red[0] + red[1] + red[2] + red[3]);  // ~ sigma_max(S)^2
    float inv = 1.0f / lam;
    for (int r = tid; r < 512; r += 256) v[r] *= inv;
    __syncthreads();
  }
  if (tid == 0) alpha[n] = 2.0f / (2.0f + 1.2f * lam);
}

// ---------------- 3a) X0 = alpha * M^T ----------------
__global__ __launch_bounds__(256) void k_init_X0(const float* __restrict__ M,
                                                 const float* __restrict__ alpha,
                                                 float* __restrict__ X) {
  int idx = blockIdx.x * 256 + threadIdx.x;
  int n = idx >> 18, r = (idx >> 9) & 511, c = idx & 511;
  X[idx] = alpha[n] * M[(n << 18) | (c << 9) | r];
}

// ---------------- small batched MFMA matmul ----------------
// C = sgn * (A @ B) + c1 * D   (per batch z; 128x128 tile, BK=32)
// SPLIT: 3-MFMA hi/lo emulation (~fp21 product precision)
template <int SPLIT, int BF16OUT>
__global__ __launch_bounds__(256)
void k_smm(const float* __restrict__ A, int lda, long long astride,
           const float* __restrict__ B, int ldb, long long bstride,
           void* __restrict__ Cv, int ldc, long long cstride,
           const float* __restrict__ D, int ldd, long long dstride,
           float c1, float sgn, int K) {
  __shared__ __align__(16) u16 lA  [128 * 40];
  __shared__ __align__(16) u16 lBT [128 * 40];
  __shared__ __align__(16) u16 lAl [SPLIT ? 128 * 40 : 8];
  __shared__ __align__(16) u16 lBTl[SPLIT ? 128 * 40 : 8];

  const int nz = blockIdx.z;
  const float* Ab = A + (size_t)nz * astride;
  const float* Bb = B + (size_t)nz * bstride;
  const float* Db = D + (size_t)nz * dstride;
  const int tid = threadIdx.x, lane = tid & 63, wave = tid >> 6;
  const int m0 = blockIdx.y * 128, n0 = blockIdx.x * 128;
  const int wr = wave >> 1, wc = wave & 1;
  f32x4 acc[4][4] = {};

  for (int k0 = 0; k0 < K; k0 += 32) {
    if (k0) __syncthreads();
    {  // stage A tile [128 x 32], rows k-contiguous
      const int row = tid >> 1, ks = (tid & 1) * 16;
      const float* src = Ab + (size_t)(m0 + row) * lda + k0 + ks;
      float fv[16];
#pragma unroll
      for (int q = 0; q < 4; ++q) {
        float4 f = *(reinterpret_cast<const float4*>(src) + q);
        fv[q * 4 + 0] = f.x; fv[q * 4 + 1] = f.y; fv[q * 4 + 2] = f.z; fv[q * 4 + 3] = f.w;
      }
      u16 hv[16];
#pragma unroll
      for (int e = 0; e < 16; ++e) hv[e] = f2bf(fv[e]);
      u16x8 w0, w1;
#pragma unroll
      for (int e = 0; e < 8; ++e) { w0[e] = hv[e]; w1[e] = hv[e + 8]; }
      *reinterpret_cast<u16x8*>(&lA[row * 40 + ks])     = w0;
      *reinterpret_cast<u16x8*>(&lA[row * 40 + ks + 8]) = w1;
      if constexpr (SPLIT) {
        u16 hl[16];
#pragma unroll
        for (int e = 0; e < 16; ++e) hl[e] = f2bf(fv[e] - bf2f(hv[e]));
        u16x8 l0, l1;
#pragma unroll
        for (int e = 0; e < 8; ++e) { l0[e] = hl[e]; l1[e] = hl[e + 8]; }
        *reinterpret_cast<u16x8*>(&lAl[row * 40 + ks])     = l0;
        *reinterpret_cast<u16x8*>(&lAl[row * 40 + ks + 8]) = l1;
      }
    }
    {  // stage B tile transposed: lBT[n][k]
      const int kk = tid >> 3, nb = (tid & 7) * 16;
      const float* src = Bb + (size_t)(k0 + kk) * ldb + n0 + nb;
      float fv[16];
#pragma unroll
      for (int q = 0; q < 4; ++q) {
        float4 f = *(reinterpret_cast<const float4*>(src) + q);
        fv[q * 4 + 0] = f.x; fv[q * 4 + 1] = f.y; fv[q * 4 + 2] = f.z; fv[q * 4 + 3] = f.w;
      }
#pragma unroll
      for (int e = 0; e < 16; ++e) {
        u16 h = f2bf(fv[e]);
        lBT[(nb + e) * 40 + kk] = h;
        if constexpr (SPLIT) lBTl[(nb + e) * 40 + kk] = f2bf(fv[e] - bf2f(h));
      }
    }
    __syncthreads();
    const int ks = (lane >> 4) * 8;
    bf16x8 af[4], bfr[4], afl[4], bfl[4];
#pragma unroll
    for (int f = 0; f < 4; ++f) {
      const int ar = wr * 64 + f * 16 + (lane & 15);
      const int bc = wc * 64 + f * 16 + (lane & 15);
      af[f]  = *reinterpret_cast<const bf16x8*>(&lA [ar * 40 + ks]);
      bfr[f] = *reinterpret_cast<const bf16x8*>(&lBT[bc * 40 + ks]);
      if constexpr (SPLIT) {
        afl[f] = *reinterpret_cast<const bf16x8*>(&lAl [ar * 40 + ks]);
        bfl[f] = *reinterpret_cast<const bf16x8*>(&lBTl[bc * 40 + ks]);
      }
    }
#pragma unroll
    for (int i = 0; i < 4; ++i)
#pragma unroll
      for (int j = 0; j < 4; ++j) {
        acc[i][j] = __builtin_amdgcn_mfma_f32_16x16x32_bf16(af[i], bfr[j], acc[i][j], 0, 0, 0);
        if constexpr (SPLIT) {
          acc[i][j] = __builtin_amdgcn_mfma_f32_16x16x32_bf16(af[i],  bfl[j], acc[i][j], 0, 0, 0);
          acc[i][j] = __builtin_amdgcn_mfma_f32_16x16x32_bf16(afl[i], bfr[j], acc[i][j], 0, 0, 0);
        }
      }
  }
  // epilogue: C = sgn*acc + c1*D   (C/D frag map: col=lane&15, row=(lane>>4)*4+r)
#pragma unroll
  for (int i = 0; i < 4; ++i) {
    const int rowb = m0 + wr * 64 + i * 16 + ((lane >> 4) << 2);
#pragma unroll
    for (int j = 0; j < 4; ++j) {
      const int col = n0 + wc * 64 + j * 16 + (lane & 15);
#pragma unroll
      for (int r = 0; r < 4; ++r) {
        float val = sgn * acc[i][j][r];
        if (c1 != 0.0f) val += c1 * Db[(size_t)(rowb + r) * ldd + col];
        if constexpr (BF16OUT)
          reinterpret_cast<u16*>(Cv)[(size_t)nz * cstride + (size_t)(rowb + r) * ldc + col] = f2bf(val);
        else
          reinterpret_cast<float*>(Cv)[(size_t)nz * cstride + (size_t)(rowb + r) * ldc + col] = val;
      }
    }
  }
}

// ---------------- 5a) x (f32) -> bf16 ----------------
__global__ __launch_bounds__(256) void k_f32_to_bf16(const float* __restrict__ in,
                                                     u16* __restrict__ out) {
  int idx = blockIdx.x * 256 + threadIdx.x;  // 8 elements per thread
  const float* src = in + (size_t)idx * 8;
  float4 f0 = *reinterpret_cast<const float4*>(src);
  float4 f1 = *reinterpret_cast<const float4*>(src + 4);
  u16x8 w;
  w[0] = f2bf(f0.x); w[1] = f2bf(f0.y); w[2] = f2bf(f0.z); w[3] = f2bf(f0.w);
  w[4] = f2bf(f1.x); w[5] = f2bf(f1.y); w[6] = f2bf(f1.z); w[7] = f2bf(f1.w);
  *reinterpret_cast<u16x8*>(out + (size_t)idx * 8) = w;
}

// ---------------- 5b) out = x_bf @ tw^T + bias  (128x128, BK=64) ----------------
__global__ __launch_bounds__(256)
void k_gemm_bt_bias(const u16* __restrict__ A,   // x_bf [8192][4096]
                    const u16* __restrict__ B,   // tw_bf [4096][4096]
                    const float* __restrict__ bias,
                    float* __restrict__ C, int Ncols, int K) {
  __shared__ __align__(16) u16 lA[128 * 64];
  __shared__ __align__(16) u16 lB[128 * 64];
  const int tid = threadIdx.x, lane = tid & 63, wave = tid >> 6;
  const int m0 = blockIdx.y * 128, n0 = blockIdx.x * 128;
  const int wr = wave >> 1, wc = wave & 1;
  f32x4 acc[4][4] = {};
  const u16* aBase = A + (size_t)m0 * K;
  const u16* bBase = B + (size_t)n0 * K;
  const int rowA = lane >> 3, kb = (lane & 7) * 8;

  for (int k0 = 0; k0 < K; k0 += 64) {
#pragma unroll
    for (int c = 0; c < 4; ++c) {
      const int chunk = wave * 4 + c;                     // wave-uniform
      const u16* ga = aBase + (size_t)(chunk * 8 + rowA) * K + k0 + kb;
      __builtin_amdgcn_global_load_lds(
          (const __attribute__((address_space(1))) void*)ga,
          (__attribute__((address_space(3))) void*)(lA + chunk * 512), 16, 0, 0);
      const u16* gb = bBase + (size_t)(chunk * 8 + rowA) * K + k0 + kb;
      __builtin_amdgcn_global_load_lds(
          (const __attribute__((address_space(1))) void*)gb,
          (__attribute__((address_space(3))) void*)(lB + chunk * 512), 16, 0, 0);
    }
    __syncthreads();
#pragma unroll
    for (int kh = 0; kh < 2; ++kh) {
      const int ks = kh * 32 + (lane >> 4) * 8;
      bf16x8 af[4], bfr[4];
#pragma unroll
      for (int f = 0; f < 4; ++f) {
        const int ar = wr * 64 + f * 16 + (lane & 15);
        const int bc = wc * 64 + f * 16 + (lane & 15);
        af[f]  = *reinterpret_cast<const bf16x8*>(&lA[ar * 64 + ks]);
        bfr[f] = *reinterpret_cast<const bf16x8*>(&lB[bc * 64 + ks]);
      }
#pragma unroll
      for (int i = 0; i < 4; ++i)
#pragma unroll
        for (int j = 0; j < 4; ++j)
          acc[i][j] = __builtin_amdgcn_mfma_f32_16x16x32_bf16(af[i], bfr[j], acc[i][j], 0, 0, 0);
    }
    __syncthreads();
  }
#pragma unroll
  for (int j = 0; j < 4; ++j) {
    const int col = n0 + wc * 64 + j * 16 + (lane & 15);
    const float bv = bias[col];
#pragma unroll
    for (int i = 0; i < 4; ++i) {
      const int rowb = m0 + wr * 64 + i * 16 + ((lane >> 4) << 2);
#pragma unroll
      for (int r = 0; r < 4; ++r)
        C[(size_t)(rowb + r) * Ncols + col] = acc[i][j][r] + bv;
    }
  }
}

extern "C" void kernel_launch(void* const* d_in, const int* in_sizes, int n_in,
                              void* d_out, int out_size, void* d_ws, size_t ws_size,
                              hipStream_t stream) {
  const float* W    = (const float*)d_in[0];   // [4096,4096]
  const float* bias = (const float*)d_in[1];   // [4096]
  const float* x    = (const float*)d_in[2];   // [4,2048,4096]
  const float* R    = (const float*)d_in[3];   // [8,512,512]
  float* out = (float*)d_out;

  char* ws = (char*)d_ws;
  u16*   x_bf  = (u16*)(ws);                         //  64 MiB
  u16*   tw    = (u16*)(ws + 67108864);              //  32 MiB
  float* M     = (float*)(ws + 100663296);           //   8 MiB
  float* X     = (float*)(ws + 109051904);           //   8 MiB
  float* T     = (float*)(ws + 117440512);           //   8 MiB
  float* X2    = (float*)(ws + 125829120);           //   8 MiB
  float* alpha = (float*)(ws + 134217728);           //  32 B

  k_build_M<<<8192, 256, 0, stream>>>(R, M);
  k_power_alpha<<<8, 256, 0, stream>>>(M, alpha);
  k_init_X0<<<8192, 256, 0, stream>>>(M, alpha, X);

  const long long BS2 = 262144;  // 512*512
  dim3 gN(4, 4, 8);
  float* Xc = X;
  float* Xn = X2;
  for (int it = 0; it < 10; ++it) {   // bf16 Newton: T = M X ; X <- 2X - X T
    k_smm<0, 0><<<gN, 256, 0, stream>>>(M, 512, BS2, Xc, 512, BS2,
                                        T, 512, BS2, Xc, 512, BS2, 0.f, 1.f, 512);
    k_smm<0, 0><<<gN, 256, 0, stream>>>(Xc, 512, BS2, T, 512, BS2,
                                        Xn, 512, BS2, Xc, 512, BS2, 2.f, -1.f, 512);
    float* tmp = Xc; Xc = Xn; Xn = tmp;
  }
  // split-precision polish iteration
  k_smm<1, 0><<<gN, 256, 0, stream>>>(M, 512, BS2, Xc, 512, BS2,
                                      T, 512, BS2, Xc, 512, BS2, 0.f, 1.f, 512);
  k_smm<1, 0><<<gN, 256, 0, stream>>>(Xc, 512, BS2, T, 512, BS2,
                                      Xn, 512, BS2, Xc, 512, BS2, 2.f, -1.f, 512);
  { float* tmp = Xc; Xc = Xn; Xn = tmp; }
  // Q = (2+1e-6) X - M X   (into T)
  k_smm<1, 0><<<gN, 256, 0, stream>>>(M, 512, BS2, Xc, 512, BS2,
                                      T, 512, BS2, Xc, 512, BS2, C1Q, -1.f, 512);
  // tw = W @ blockdiag(Q), bf16 out
  dim3 gT(4, 32, 8);
  k_smm<0, 1><<<gT, 256, 0, stream>>>(W, 4096, 512, T, 512, BS2,
                                      tw, 4096, 512, W, 4096, 512, 0.f, 1.f, 512);
  // x -> bf16 ; main GEMM
  k_f32_to_bf16<<<16384, 256, 0, stream>>>(x, x_bf);
  dim3 gG(32, 64);
  k_gemm_bt_bias<<<gG, 256, 0, stream>>>(x_bf, tw, bias, out, 4096, 4096);
}

// Round 2
// 1172.760 us; speedup vs baseline: 2.6053x; 2.6053x over previous
//
#include <hip/hip_runtime.h>
#include <hip/hip_bf16.h>

// EnhancedOFTLinearLayer: out = x @ (W @ blockdiag(cayley(R)))^T + bias
//   cayley(A): S = 0.5(A - A^T); Q = (I - S) @ inv((1+1e-6)I + S)
// Pipeline (round 1 — no power iteration):
//   1) build M = (1+1e-6)I + S
//   2) H = M^T M = -M@M + 2c0 M ; H2 = H@H ; H4 = H2@H2 ;
//      lambda_hat = (||H4||_F^2)^(1/8) >= lambda_max(H)  [guaranteed bound]
//      alpha = 2 / (c0^2 + lambda_hat)
//   3) X0 = alpha*M^T = alpha*(2c0 I - M); 6x bf16 Newton X<-X(2I-MX);
//      1x split-precision polish; Q = (2+1e-6)X - M@X
//   4) tw = W @ blockdiag(Q)  (bf16 out)
//   5) x -> bf16 ; out = x_bf @ tw^T + bias  (m97-style 128x128 MFMA GEMM)

typedef unsigned short u16;
typedef __attribute__((ext_vector_type(8))) __bf16 bf16x8;
typedef __attribute__((ext_vector_type(4))) float f32x4;
typedef __attribute__((ext_vector_type(8))) unsigned short u16x8;

#define C0   1.000001f   /* 1 + 1e-6 */
#define C1Q  2.000001f   /* 1 + C0   */

__device__ __forceinline__ u16 f2bf(float x) {
  union { float f; unsigned u; } v; v.f = x;
  return (u16)((v.u + 0x7fffu + ((v.u >> 16) & 1u)) >> 16);
}
__device__ __forceinline__ float bf2f(u16 h) {
  union { float f; unsigned u; } v; v.u = ((unsigned)h) << 16; return v.f;
}

// ---------------- 1) M = (1+1e-6)I + 0.5(R - R^T) ----------------
__global__ __launch_bounds__(256) void k_build_M(const float* __restrict__ R,
                                                 float* __restrict__ M) {
  int idx = blockIdx.x * 256 + threadIdx.x;          // 8*512*512 total
  int n = idx >> 18, r = (idx >> 9) & 511, c = idx & 511;
  float a  = R[idx];
  float at = R[(n << 18) | (c << 9) | r];
  float s  = 0.5f * (a - at);
  M[idx] = s + (r == c ? C0 : 0.0f);
}

// ---------------- 2b) alpha[n] = 2/(c0^2 + (||H4||_F^2)^(1/8)) ----------------
__global__ __launch_bounds__(1024) void k_frob_alpha(const float* __restrict__ H4,
                                                     float* __restrict__ alpha) {
  __shared__ float red[16];
  const int n = blockIdx.x, tid = threadIdx.x;
  const float* src = H4 + (size_t)n * 262144;
  float s = 0.f;
  for (int i = tid; i < 65536; i += 1024) {
    float4 f = reinterpret_cast<const float4*>(src)[i];
    s += f.x * f.x + f.y * f.y + f.z * f.z + f.w * f.w;
  }
  for (int off = 32; off; off >>= 1) s += __shfl_down(s, off, 64);
  if ((tid & 63) == 0) red[tid >> 6] = s;
  __syncthreads();
  if (tid == 0) {
    float t = 0.f;
    for (int q = 0; q < 16; ++q) t += red[q];
    float lam = powf(t, 0.125f);            // >= lambda_max(M^T M)
    alpha[n] = 2.0f / (C0 * C0 + lam);
  }
}

// ---------------- 3a) X0 = alpha * M^T = alpha * (2c0 I - M) ----------------
__global__ __launch_bounds__(256) void k_init_X0(const float* __restrict__ M,
                                                 const float* __restrict__ alpha,
                                                 float* __restrict__ X) {
  int idx = blockIdx.x * 256 + threadIdx.x;
  int n = idx >> 18, r = (idx >> 9) & 511, c = idx & 511;
  X[idx] = alpha[n] * ((r == c ? 2.0f * C0 : 0.0f) - M[idx]);
}

// ---------------- small batched MFMA matmul ----------------
// C = sgn * (A @ B) + c1 * D   (per batch z; 128x128 tile, BK=32)
// SPLIT: 3-MFMA hi/lo emulation (~fp21 product precision)
template <int SPLIT, int BF16OUT>
__global__ __launch_bounds__(256)
void k_smm(const float* __restrict__ A, int lda, long long astride,
           const float* __restrict__ B, int ldb, long long bstride,
           void* __restrict__ Cv, int ldc, long long cstride,
           const float* __restrict__ D, int ldd, long long dstride,
           float c1, float sgn, int K) {
  __shared__ __align__(16) u16 lA  [128 * 40];
  __shared__ __align__(16) u16 lBT [128 * 40];
  __shared__ __align__(16) u16 lAl [SPLIT ? 128 * 40 : 8];
  __shared__ __align__(16) u16 lBTl[SPLIT ? 128 * 40 : 8];

  const int nz = blockIdx.z;
  const float* Ab = A + (size_t)nz * astride;
  const float* Bb = B + (size_t)nz * bstride;
  const float* Db = D + (size_t)nz * dstride;
  const int tid = threadIdx.x, lane = tid & 63, wave = tid >> 6;
  const int m0 = blockIdx.y * 128, n0 = blockIdx.x * 128;
  const int wr = wave >> 1, wc = wave & 1;
  f32x4 acc[4][4] = {};

  for (int k0 = 0; k0 < K; k0 += 32) {
    if (k0) __syncthreads();
    {  // stage A tile [128 x 32], rows k-contiguous
      const int row = tid >> 1, ks = (tid & 1) * 16;
      const float* src = Ab + (size_t)(m0 + row) * lda + k0 + ks;
      float fv[16];
#pragma unroll
      for (int q = 0; q < 4; ++q) {
        float4 f = *(reinterpret_cast<const float4*>(src) + q);
        fv[q * 4 + 0] = f.x; fv[q * 4 + 1] = f.y; fv[q * 4 + 2] = f.z; fv[q * 4 + 3] = f.w;
      }
      u16 hv[16];
#pragma unroll
      for (int e = 0; e < 16; ++e) hv[e] = f2bf(fv[e]);
      u16x8 w0, w1;
#pragma unroll
      for (int e = 0; e < 8; ++e) { w0[e] = hv[e]; w1[e] = hv[e + 8]; }
      *reinterpret_cast<u16x8*>(&lA[row * 40 + ks])     = w0;
      *reinterpret_cast<u16x8*>(&lA[row * 40 + ks + 8]) = w1;
      if constexpr (SPLIT) {
        u16 hl[16];
#pragma unroll
        for (int e = 0; e < 16; ++e) hl[e] = f2bf(fv[e] - bf2f(hv[e]));
        u16x8 l0, l1;
#pragma unroll
        for (int e = 0; e < 8; ++e) { l0[e] = hl[e]; l1[e] = hl[e + 8]; }
        *reinterpret_cast<u16x8*>(&lAl[row * 40 + ks])     = l0;
        *reinterpret_cast<u16x8*>(&lAl[row * 40 + ks + 8]) = l1;
      }
    }
    {  // stage B tile transposed: lBT[n][k]
      const int kk = tid >> 3, nb = (tid & 7) * 16;
      const float* src = Bb + (size_t)(k0 + kk) * ldb + n0 + nb;
      float fv[16];
#pragma unroll
      for (int q = 0; q < 4; ++q) {
        float4 f = *(reinterpret_cast<const float4*>(src) + q);
        fv[q * 4 + 0] = f.x; fv[q * 4 + 1] = f.y; fv[q * 4 + 2] = f.z; fv[q * 4 + 3] = f.w;
      }
#pragma unroll
      for (int e = 0; e < 16; ++e) {
        u16 h = f2bf(fv[e]);
        lBT[(nb + e) * 40 + kk] = h;
        if constexpr (SPLIT) lBTl[(nb + e) * 40 + kk] = f2bf(fv[e] - bf2f(h));
      }
    }
    __syncthreads();
    const int ks = (lane >> 4) * 8;
    bf16x8 af[4], bfr[4], afl[4], bfl[4];
#pragma unroll
    for (int f = 0; f < 4; ++f) {
      const int ar = wr * 64 + f * 16 + (lane & 15);
      const int bc = wc * 64 + f * 16 + (lane & 15);
      af[f]  = *reinterpret_cast<const bf16x8*>(&lA [ar * 40 + ks]);
      bfr[f] = *reinterpret_cast<const bf16x8*>(&lBT[bc * 40 + ks]);
      if constexpr (SPLIT) {
        afl[f] = *reinterpret_cast<const bf16x8*>(&lAl [ar * 40 + ks]);
        bfl[f] = *reinterpret_cast<const bf16x8*>(&lBTl[bc * 40 + ks]);
      }
    }
#pragma unroll
    for (int i = 0; i < 4; ++i)
#pragma unroll
      for (int j = 0; j < 4; ++j) {
        acc[i][j] = __builtin_amdgcn_mfma_f32_16x16x32_bf16(af[i], bfr[j], acc[i][j], 0, 0, 0);
        if constexpr (SPLIT) {
          acc[i][j] = __builtin_amdgcn_mfma_f32_16x16x32_bf16(af[i],  bfl[j], acc[i][j], 0, 0, 0);
          acc[i][j] = __builtin_amdgcn_mfma_f32_16x16x32_bf16(afl[i], bfr[j], acc[i][j], 0, 0, 0);
        }
      }
  }
  // epilogue: C = sgn*acc + c1*D   (C/D frag map: col=lane&15, row=(lane>>4)*4+r)
#pragma unroll
  for (int i = 0; i < 4; ++i) {
    const int rowb = m0 + wr * 64 + i * 16 + ((lane >> 4) << 2);
#pragma unroll
    for (int j = 0; j < 4; ++j) {
      const int col = n0 + wc * 64 + j * 16 + (lane & 15);
#pragma unroll
      for (int r = 0; r < 4; ++r) {
        float val = sgn * acc[i][j][r];
        if (c1 != 0.0f) val += c1 * Db[(size_t)(rowb + r) * ldd + col];
        if constexpr (BF16OUT)
          reinterpret_cast<u16*>(Cv)[(size_t)nz * cstride + (size_t)(rowb + r) * ldc + col] = f2bf(val);
        else
          reinterpret_cast<float*>(Cv)[(size_t)nz * cstride + (size_t)(rowb + r) * ldc + col] = val;
      }
    }
  }
}

// ---------------- 5a) x (f32) -> bf16 ----------------
__global__ __launch_bounds__(256) void k_f32_to_bf16(const float* __restrict__ in,
                                                     u16* __restrict__ out) {
  int idx = blockIdx.x * 256 + threadIdx.x;  // 8 elements per thread
  const float* src = in + (size_t)idx * 8;
  float4 f0 = *reinterpret_cast<const float4*>(src);
  float4 f1 = *reinterpret_cast<const float4*>(src + 4);
  u16x8 w;
  w[0] = f2bf(f0.x); w[1] = f2bf(f0.y); w[2] = f2bf(f0.z); w[3] = f2bf(f0.w);
  w[4] = f2bf(f1.x); w[5] = f2bf(f1.y); w[6] = f2bf(f1.z); w[7] = f2bf(f1.w);
  *reinterpret_cast<u16x8*>(out + (size_t)idx * 8) = w;
}

// ---------------- 5b) out = x_bf @ tw^T + bias  (128x128, BK=64) ----------------
__global__ __launch_bounds__(256)
void k_gemm_bt_bias(const u16* __restrict__ A,   // x_bf [8192][4096]
                    const u16* __restrict__ B,   // tw_bf [4096][4096]
                    const float* __restrict__ bias,
                    float* __restrict__ C, int Ncols, int K) {
  __shared__ __align__(16) u16 lA[128 * 64];
  __shared__ __align__(16) u16 lB[128 * 64];
  const int tid = threadIdx.x, lane = tid & 63, wave = tid >> 6;
  const int m0 = blockIdx.y * 128, n0 = blockIdx.x * 128;
  const int wr = wave >> 1, wc = wave & 1;
  f32x4 acc[4][4] = {};
  const u16* aBase = A + (size_t)m0 * K;
  const u16* bBase = B + (size_t)n0 * K;
  const int rowA = lane >> 3, kb = (lane & 7) * 8;

  for (int k0 = 0; k0 < K; k0 += 64) {
#pragma unroll
    for (int c = 0; c < 4; ++c) {
      const int chunk = wave * 4 + c;                     // wave-uniform
      const u16* ga = aBase + (size_t)(chunk * 8 + rowA) * K + k0 + kb;
      __builtin_amdgcn_global_load_lds(
          (const __attribute__((address_space(1))) void*)ga,
          (__attribute__((address_space(3))) void*)(lA + chunk * 512), 16, 0, 0);
      const u16* gb = bBase + (size_t)(chunk * 8 + rowA) * K + k0 + kb;
      __builtin_amdgcn_global_load_lds(
          (const __attribute__((address_space(1))) void*)gb,
          (__attribute__((address_space(3))) void*)(lB + chunk * 512), 16, 0, 0);
    }
    __syncthreads();
#pragma unroll
    for (int kh = 0; kh < 2; ++kh) {
      const int ks = kh * 32 + (lane >> 4) * 8;
      bf16x8 af[4], bfr[4];
#pragma unroll
      for (int f = 0; f < 4; ++f) {
        const int ar = wr * 64 + f * 16 + (lane & 15);
        const int bc = wc * 64 + f * 16 + (lane & 15);
        af[f]  = *reinterpret_cast<const bf16x8*>(&lA[ar * 64 + ks]);
        bfr[f] = *reinterpret_cast<const bf16x8*>(&lB[bc * 64 + ks]);
      }
#pragma unroll
      for (int i = 0; i < 4; ++i)
#pragma unroll
        for (int j = 0; j < 4; ++j)
          acc[i][j] = __builtin_amdgcn_mfma_f32_16x16x32_bf16(af[i], bfr[j], acc[i][j], 0, 0, 0);
      }
    __syncthreads();
  }
#pragma unroll
  for (int j = 0; j < 4; ++j) {
    const int col = n0 + wc * 64 + j * 16 + (lane & 15);
    const float bv = bias[col];
#pragma unroll
    for (int i = 0; i < 4; ++i) {
      const int rowb = m0 + wr * 64 + i * 16 + ((lane >> 4) << 2);
#pragma unroll
      for (int r = 0; r < 4; ++r)
        C[(size_t)(rowb + r) * Ncols + col] = acc[i][j][r] + bv;
    }
  }
}

extern "C" void kernel_launch(void* const* d_in, const int* in_sizes, int n_in,
                              void* d_out, int out_size, void* d_ws, size_t ws_size,
                              hipStream_t stream) {
  const float* W    = (const float*)d_in[0];   // [4096,4096]
  const float* bias = (const float*)d_in[1];   // [4096]
  const float* x    = (const float*)d_in[2];   // [4,2048,4096]
  const float* R    = (const float*)d_in[3];   // [8,512,512]
  float* out = (float*)d_out;

  char* ws = (char*)d_ws;
  u16*   x_bf  = (u16*)(ws);                         //  64 MiB
  u16*   tw    = (u16*)(ws + 67108864);              //  32 MiB
  float* M     = (float*)(ws + 100663296);           //   8 MiB
  float* X     = (float*)(ws + 109051904);           //   8 MiB
  float* T     = (float*)(ws + 117440512);           //   8 MiB
  float* X2    = (float*)(ws + 125829120);           //   8 MiB
  float* alpha = (float*)(ws + 134217728);           //  32 B

  const long long BS2 = 262144;  // 512*512
  dim3 gN(4, 4, 8);

  // M = c0 I + S
  k_build_M<<<8192, 256, 0, stream>>>(R, M);
  // H = M^T M = -M@M + 2c0 M   (into T)
  k_smm<0, 0><<<gN, 256, 0, stream>>>(M, 512, BS2, M, 512, BS2,
                                      T, 512, BS2, M, 512, BS2, 2.0f * C0, -1.f, 512);
  // H2 = H@H (into X) ; H4 = H2@H2 (into X2)
  k_smm<0, 0><<<gN, 256, 0, stream>>>(T, 512, BS2, T, 512, BS2,
                                      X, 512, BS2, T, 512, BS2, 0.f, 1.f, 512);
  k_smm<0, 0><<<gN, 256, 0, stream>>>(X, 512, BS2, X, 512, BS2,
                                      X2, 512, BS2, X, 512, BS2, 0.f, 1.f, 512);
  // alpha[n] from tr(H^8) = ||H4||_F^2
  k_frob_alpha<<<8, 1024, 0, stream>>>(X2, alpha);
  // X0 = alpha * (2c0 I - M)   (into X; H2 dead)
  k_init_X0<<<8192, 256, 0, stream>>>(M, alpha, X);

  float* Xc = X;
  float* Xn = X2;
  for (int it = 0; it < 6; ++it) {   // bf16 Newton: T = M X ; X <- 2X - X T
    k_smm<0, 0><<<gN, 256, 0, stream>>>(M, 512, BS2, Xc, 512, BS2,
                                        T, 512, BS2, Xc, 512, BS2, 0.f, 1.f, 512);
    k_smm<0, 0><<<gN, 256, 0, stream>>>(Xc, 512, BS2, T, 512, BS2,
                                        Xn, 512, BS2, Xc, 512, BS2, 2.f, -1.f, 512);
    float* tmp = Xc; Xc = Xn; Xn = tmp;
  }
  // split-precision polish iteration
  k_smm<1, 0><<<gN, 256, 0, stream>>>(M, 512, BS2, Xc, 512, BS2,
                                      T, 512, BS2, Xc, 512, BS2, 0.f, 1.f, 512);
  k_smm<1, 0><<<gN, 256, 0, stream>>>(Xc, 512, BS2, T, 512, BS2,
                                      Xn, 512, BS2, Xc, 512, BS2, 2.f, -1.f, 512);
  { float* tmp = Xc; Xc = Xn; Xn = tmp; }
  // Q = (2+1e-6) X - M X   (into T)
  k_smm<1, 0><<<gN, 256, 0, stream>>>(M, 512, BS2, Xc, 512, BS2,
                                      T, 512, BS2, Xc, 512, BS2, C1Q, -1.f, 512);
  // tw = W @ blockdiag(Q), bf16 out
  dim3 gT(4, 32, 8);
  k_smm<0, 1><<<gT, 256, 0, stream>>>(W, 4096, 512, T, 512, BS2,
                                      tw, 4096, 512, W, 4096, 512, 0.f, 1.f, 512);
  // x -> bf16 ; main GEMM
  k_f32_to_bf16<<<16384, 256, 0, stream>>>(x, x_bf);
  dim3 gG(32, 64);
  k_gemm_bt_bias<<<gG, 256, 0, stream>>>(x_bf, tw, bias, out, 4096, 4096);
}

// Round 4
// 1033.391 us; speedup vs baseline: 2.9566x; 1.1349x over previous
//
#include <hip/hip_runtime.h>
#include <hip/hip_bf16.h>

// EnhancedOFTLinearLayer: out = x @ (W @ blockdiag(cayley(R)))^T + bias
//   cayley(A): S = 0.5(A - A^T); Q = (I - S) @ inv((1+1e-6)I + S)
// Round 3: fix end-of-pipeline vmcnt drain (peel last 2 K-tiles: vmcnt(2) /
// vmcnt(0) / none). 256x256 4-phase schedule, counted vmcnt, T2 granule-XOR
// swizzle, T1 XCD swizzle, T5 setprio.

typedef unsigned short u16;
typedef __attribute__((ext_vector_type(8))) __bf16 bf16x8;
typedef __attribute__((ext_vector_type(4))) float f32x4;
typedef __attribute__((ext_vector_type(8))) unsigned short u16x8;

#define C0   1.000001f   /* 1 + 1e-6 */
#define C1Q  2.000001f   /* 1 + C0   */

__device__ __forceinline__ u16 f2bf(float x) {
  union { float f; unsigned u; } v; v.f = x;
  return (u16)((v.u + 0x7fffu + ((v.u >> 16) & 1u)) >> 16);
}
__device__ __forceinline__ float bf2f(u16 h) {
  union { float f; unsigned u; } v; v.u = ((unsigned)h) << 16; return v.f;
}

// ---------------- 1) M = (1+1e-6)I + 0.5(R - R^T)  (tiled, coalesced) -------
__global__ __launch_bounds__(256) void k_build_M(const float* __restrict__ R,
                                                 float* __restrict__ M) {
  __shared__ float t1[32][33];
  const int n = blockIdx.z;
  const int tr = blockIdx.y * 32, tc = blockIdx.x * 32;
  const int ly = threadIdx.x >> 5, lx = threadIdx.x & 31;   // 8 x 32
  const float* Rb = R + (size_t)n * 262144;
  float a[4];
#pragma unroll
  for (int i = 0; i < 4; ++i) {
    a[i] = Rb[(size_t)(tr + ly + i * 8) * 512 + tc + lx];
    t1[ly + i * 8][lx] = Rb[(size_t)(tc + ly + i * 8) * 512 + tr + lx];
  }
  __syncthreads();
#pragma unroll
  for (int i = 0; i < 4; ++i) {
    const int r = tr + ly + i * 8, c = tc + lx;
    float s = 0.5f * (a[i] - t1[lx][ly + i * 8]);
    M[(size_t)n * 262144 + (size_t)r * 512 + c] = s + (r == c ? C0 : 0.0f);
  }
}

// ---------------- 2b) alpha[n] = 2/(c0^2 + (||H4||_F^2)^(1/8)) ----------------
__global__ __launch_bounds__(1024) void k_frob_alpha(const float* __restrict__ H4,
                                                     float* __restrict__ alpha) {
  __shared__ float red[16];
  const int n = blockIdx.x, tid = threadIdx.x;
  const float* src = H4 + (size_t)n * 262144;
  float s = 0.f;
  for (int i = tid; i < 65536; i += 1024) {
    float4 f = reinterpret_cast<const float4*>(src)[i];
    s += f.x * f.x + f.y * f.y + f.z * f.z + f.w * f.w;
  }
  for (int off = 32; off; off >>= 1) s += __shfl_down(s, off, 64);
  if ((tid & 63) == 0) red[tid >> 6] = s;
  __syncthreads();
  if (tid == 0) {
    float t = 0.f;
    for (int q = 0; q < 16; ++q) t += red[q];
    float lam = powf(t, 0.125f);            // >= lambda_max(M^T M)
    alpha[n] = 2.0f / (C0 * C0 + lam);
  }
}

// ---------------- 3a) X0 = alpha * M^T = alpha * (2c0 I - M) ----------------
__global__ __launch_bounds__(256) void k_init_X0(const float* __restrict__ M,
                                                 const float* __restrict__ alpha,
                                                 float* __restrict__ X) {
  int idx = blockIdx.x * 256 + threadIdx.x;
  int n = idx >> 18, r = (idx >> 9) & 511, c = idx & 511;
  X[idx] = alpha[n] * ((r == c ? 2.0f * C0 : 0.0f) - M[idx]);
}

// ---------------- small batched MFMA matmul ----------------
// C = sgn * (A @ B) + c1 * D   (per batch z; 128x128 tile, BK=32)
template <int SPLIT, int BF16OUT>
__global__ __launch_bounds__(256)
void k_smm(const float* __restrict__ A, int lda, long long astride,
           const float* __restrict__ B, int ldb, long long bstride,
           void* __restrict__ Cv, int ldc, long long cstride,
           const float* __restrict__ D, int ldd, long long dstride,
           float c1, float sgn, int K) {
  __shared__ __align__(16) u16 lA  [128 * 40];
  __shared__ __align__(16) u16 lBT [128 * 40];
  __shared__ __align__(16) u16 lAl [SPLIT ? 128 * 40 : 8];
  __shared__ __align__(16) u16 lBTl[SPLIT ? 128 * 40 : 8];

  const int nz = blockIdx.z;
  const float* Ab = A + (size_t)nz * astride;
  const float* Bb = B + (size_t)nz * bstride;
  const float* Db = D + (size_t)nz * dstride;
  const int tid = threadIdx.x, lane = tid & 63, wave = tid >> 6;
  const int m0 = blockIdx.y * 128, n0 = blockIdx.x * 128;
  const int wr = wave >> 1, wc = wave & 1;
  f32x4 acc[4][4] = {};

  for (int k0 = 0; k0 < K; k0 += 32) {
    if (k0) __syncthreads();
    {  // stage A tile [128 x 32], rows k-contiguous
      const int row = tid >> 1, ks = (tid & 1) * 16;
      const float* src = Ab + (size_t)(m0 + row) * lda + k0 + ks;
      float fv[16];
#pragma unroll
      for (int q = 0; q < 4; ++q) {
        float4 f = *(reinterpret_cast<const float4*>(src) + q);
        fv[q * 4 + 0] = f.x; fv[q * 4 + 1] = f.y; fv[q * 4 + 2] = f.z; fv[q * 4 + 3] = f.w;
      }
      u16 hv[16];
#pragma unroll
      for (int e = 0; e < 16; ++e) hv[e] = f2bf(fv[e]);
      u16x8 w0, w1;
#pragma unroll
      for (int e = 0; e < 8; ++e) { w0[e] = hv[e]; w1[e] = hv[e + 8]; }
      *reinterpret_cast<u16x8*>(&lA[row * 40 + ks])     = w0;
      *reinterpret_cast<u16x8*>(&lA[row * 40 + ks + 8]) = w1;
      if constexpr (SPLIT) {
        u16 hl[16];
#pragma unroll
        for (int e = 0; e < 16; ++e) hl[e] = f2bf(fv[e] - bf2f(hv[e]));
        u16x8 l0, l1;
#pragma unroll
        for (int e = 0; e < 8; ++e) { l0[e] = hl[e]; l1[e] = hl[e + 8]; }
        *reinterpret_cast<u16x8*>(&lAl[row * 40 + ks])     = l0;
        *reinterpret_cast<u16x8*>(&lAl[row * 40 + ks + 8]) = l1;
      }
    }
    {  // stage B tile transposed: lBT[n][k]
      const int kk = tid >> 3, nb = (tid & 7) * 16;
      const float* src = Bb + (size_t)(k0 + kk) * ldb + n0 + nb;
      float fv[16];
#pragma unroll
      for (int q = 0; q < 4; ++q) {
        float4 f = *(reinterpret_cast<const float4*>(src) + q);
        fv[q * 4 + 0] = f.x; fv[q * 4 + 1] = f.y; fv[q * 4 + 2] = f.z; fv[q * 4 + 3] = f.w;
      }
#pragma unroll
      for (int e = 0; e < 16; ++e) {
        u16 h = f2bf(fv[e]);
        lBT[(nb + e) * 40 + kk] = h;
        if constexpr (SPLIT) lBTl[(nb + e) * 40 + kk] = f2bf(fv[e] - bf2f(h));
      }
    }
    __syncthreads();
    const int ks = (lane >> 4) * 8;
    bf16x8 af[4], bfr[4], afl[4], bfl[4];
#pragma unroll
    for (int f = 0; f < 4; ++f) {
      const int ar = wr * 64 + f * 16 + (lane & 15);
      const int bc = wc * 64 + f * 16 + (lane & 15);
      af[f]  = *reinterpret_cast<const bf16x8*>(&lA [ar * 40 + ks]);
      bfr[f] = *reinterpret_cast<const bf16x8*>(&lBT[bc * 40 + ks]);
      if constexpr (SPLIT) {
        afl[f] = *reinterpret_cast<const bf16x8*>(&lAl [ar * 40 + ks]);
        bfl[f] = *reinterpret_cast<const bf16x8*>(&lBTl[bc * 40 + ks]);
      }
    }
#pragma unroll
    for (int i = 0; i < 4; ++i)
#pragma unroll
      for (int j = 0; j < 4; ++j) {
        acc[i][j] = __builtin_amdgcn_mfma_f32_16x16x32_bf16(af[i], bfr[j], acc[i][j], 0, 0, 0);
        if constexpr (SPLIT) {
          acc[i][j] = __builtin_amdgcn_mfma_f32_16x16x32_bf16(af[i],  bfl[j], acc[i][j], 0, 0, 0);
          acc[i][j] = __builtin_amdgcn_mfma_f32_16x16x32_bf16(afl[i], bfr[j], acc[i][j], 0, 0, 0);
        }
      }
  }
  // epilogue: C = sgn*acc + c1*D
#pragma unroll
  for (int i = 0; i < 4; ++i) {
    const int rowb = m0 + wr * 64 + i * 16 + ((lane >> 4) << 2);
#pragma unroll
    for (int j = 0; j < 4; ++j) {
      const int col = n0 + wc * 64 + j * 16 + (lane & 15);
#pragma unroll
      for (int r = 0; r < 4; ++r) {
        float val = sgn * acc[i][j][r];
        if (c1 != 0.0f) val += c1 * Db[(size_t)(rowb + r) * ldd + col];
        if constexpr (BF16OUT)
          reinterpret_cast<u16*>(Cv)[(size_t)nz * cstride + (size_t)(rowb + r) * ldc + col] = f2bf(val);
        else
          reinterpret_cast<float*>(Cv)[(size_t)nz * cstride + (size_t)(rowb + r) * ldc + col] = val;
      }
    }
  }
}

// ---------------- 5a) x (f32) -> bf16 ----------------
__global__ __launch_bounds__(256) void k_f32_to_bf16(const float* __restrict__ in,
                                                     u16* __restrict__ out) {
  int idx = blockIdx.x * 256 + threadIdx.x;  // 8 elements per thread
  const float* src = in + (size_t)idx * 8;
  float4 f0 = *reinterpret_cast<const float4*>(src);
  float4 f1 = *reinterpret_cast<const float4*>(src + 4);
  u16x8 w;
  w[0] = f2bf(f0.x); w[1] = f2bf(f0.y); w[2] = f2bf(f0.z); w[3] = f2bf(f0.w);
  w[4] = f2bf(f1.x); w[5] = f2bf(f1.y); w[6] = f2bf(f1.z); w[7] = f2bf(f1.w);
  *reinterpret_cast<u16x8*>(out + (size_t)idx * 8) = w;
}

// ---------------- 5b) out = x_bf @ tw^T + bias --------------------------------
// 256x256 tile, BK=64, 8 waves (2Mx4N), 4 phases/K-tile, 9-slot LDS ring,
// counted vmcnt, T2 granule-XOR swizzle, T5 setprio.
// WM: 0 = no wait, 1 = vmcnt(2) (steady state), 2 = vmcnt(0) (pipeline drain
// at tau == NT-2, where the just-issued stage was a no-op so the 2 allowed
// outstanding loads would be the LAST tile's B1 half -> must drain fully).
#define NSLOT 9

#define PHASE(KH, MH, WM)                                                      \
  {                                                                            \
    const int gsk = gs0 ^ ((KH) ? 4 : 0);                                      \
    if ((MH) == 0) {                                                           \
      _Pragma("unroll")                                                        \
      for (int n = 0; n < 4; ++n)                                              \
        bf[n] = *reinterpret_cast<const bf16x8*>(                              \
            &lds[bslot * 8192 + (bro + n * 16) * 64 + gsk * 8]);               \
    }                                                                          \
    _Pragma("unroll")                                                          \
    for (int m = 0; m < 4; ++m)                                                \
      af[m] = *reinterpret_cast<const bf16x8*>(                                \
          &lds[aslot * 8192 + ((MH) * 64 + m * 16 + c15) * 64 + gsk * 8]);     \
    STAGE();                                                                   \
    __builtin_amdgcn_s_barrier();                                              \
    asm volatile("s_waitcnt lgkmcnt(0)" ::: "memory");                         \
    __builtin_amdgcn_sched_barrier(0);                                         \
    __builtin_amdgcn_s_setprio(1);                                             \
    _Pragma("unroll")                                                          \
    for (int m = 0; m < 4; ++m)                                                \
      _Pragma("unroll")                                                        \
      for (int n = 0; n < 4; ++n)                                              \
        acc[(MH) * 4 + m][n] = __builtin_amdgcn_mfma_f32_16x16x32_bf16(        \
            af[m], bf[n], acc[(MH) * 4 + m][n], 0, 0, 0);                      \
    __builtin_amdgcn_s_setprio(0);                                             \
    __builtin_amdgcn_sched_barrier(0);                                         \
    if ((WM) == 1) asm volatile("s_waitcnt vmcnt(2)" ::: "memory");            \
    if ((WM) == 2) asm volatile("s_waitcnt vmcnt(0)" ::: "memory");            \
    __builtin_amdgcn_s_barrier();                                              \
  }

#define ADV()                                                                  \
  aslot += 4; if (aslot >= NSLOT) aslot -= NSLOT;                              \
  bslot += 4; if (bslot >= NSLOT) bslot -= NSLOT;

__global__ __launch_bounds__(512, 2)
void k_gemm256(const u16* __restrict__ A,   // x_bf [8192][K]
               const u16* __restrict__ B,   // tw   [4096][K]
               const float* __restrict__ bias,
               float* __restrict__ C, int N, int K) {
  __shared__ __align__(16) u16 lds[NSLOT * 8192];   // 144 KiB
  const int tid = threadIdx.x, lane = tid & 63, wave = tid >> 6;
  // T1: XCD-aware bijective swizzle (nwg = 512, divisible by 8)
  int bid = blockIdx.y * gridDim.x + blockIdx.x;
  const int cpx = (gridDim.x * gridDim.y) >> 3;
  bid = (bid & 7) * cpx + (bid >> 3);
  const int nbx = N >> 8;
  const int bx = bid % nbx, by = bid / nbx;
  const int m0 = by << 8, n0 = bx << 8;
  const int wr = wave >> 2, wc = wave & 3;          // 2 x 4 wave grid
  // staging coords (per thread): row srow, swizzled source granule
  const int srow = tid >> 3;
  const int scg  = (tid & 7) ^ (srow & 7);
  // read coords
  const int c15 = lane & 15, lq = lane >> 4;
  const int gs0 = lq ^ (lane & 7);                  // kh=0 granule slot
  const int bro = (wc & 1) * 64 + c15;              // B rowh base
  const int NT = K >> 6;

  f32x4 acc[8][4] = {};
  bf16x8 af[4], bf[4];

  int jn = 0, jslot = 0;
  auto STAGE = [&]() {
    if (jn < 4 * NT) {
      const int tau_s = jn >> 2, qh = jn & 3;
      const u16* srcb = (qh < 2)
          ? A + (size_t)(m0 + (qh & 1) * 128 + srow) * (size_t)K
          : B + (size_t)(n0 + (qh & 1) * 128 + srow) * (size_t)K;
      const u16* src = srcb + (tau_s << 6) + scg * 8;
      u16* dst = (u16*)lds + jslot * 8192 + wave * 512;
      __builtin_amdgcn_global_load_lds(
          (const __attribute__((address_space(1))) void*)src,
          (__attribute__((address_space(3))) void*)dst, 16, 0, 0);
      __builtin_amdgcn_global_load_lds(
          (const __attribute__((address_space(1))) void*)(src + (size_t)64 * K),
          (__attribute__((address_space(3))) void*)(dst + 4096), 16, 0, 0);
    }
    ++jn; jslot = (jslot == NSLOT - 1) ? 0 : jslot + 1;
  };

  // prologue: tile 0's 4 half-tiles + tile 1's A0
  STAGE(); STAGE(); STAGE(); STAGE(); STAGE();
  asm volatile("s_waitcnt vmcnt(2)" ::: "memory");
  __builtin_amdgcn_sched_barrier(0);
  __builtin_amdgcn_s_barrier();

  int aslot = wr, bslot = 2 + (wc >> 1);
  // steady state: tau = 0 .. NT-3
  for (int tau = 0; tau < NT - 2; ++tau) {
    PHASE(0, 0, 0)
    PHASE(0, 1, 0)
    PHASE(1, 0, 0)
    PHASE(1, 1, 1)
    ADV()
  }
  // tau = NT-2: the stage issued in phase 3 is a no-op -> full drain
  PHASE(0, 0, 0)
  PHASE(0, 1, 0)
  PHASE(1, 0, 0)
  PHASE(1, 1, 2)
  ADV()
  // tau = NT-1: last tile, no prefetch outstanding
  PHASE(0, 0, 0)
  PHASE(0, 1, 0)
  PHASE(1, 0, 0)
  PHASE(1, 1, 0)

  // epilogue: C = acc + bias
#pragma unroll
  for (int n = 0; n < 4; ++n) {
    const int col = n0 + wc * 64 + n * 16 + c15;
    const float bv = bias[col];
#pragma unroll
    for (int mi = 0; mi < 8; ++mi) {
      const int rowb = m0 + wr * 128 + mi * 16 + (lq << 2);
#pragma unroll
      for (int r = 0; r < 4; ++r)
        C[(size_t)(rowb + r) * N + col] = acc[mi][n][r] + bv;
    }
  }
}

extern "C" void kernel_launch(void* const* d_in, const int* in_sizes, int n_in,
                              void* d_out, int out_size, void* d_ws, size_t ws_size,
                              hipStream_t stream) {
  const float* W    = (const float*)d_in[0];   // [4096,4096]
  const float* bias = (const float*)d_in[1];   // [4096]
  const float* x    = (const float*)d_in[2];   // [4,2048,4096]
  const float* R    = (const float*)d_in[3];   // [8,512,512]
  float* out = (float*)d_out;

  char* ws = (char*)d_ws;
  u16*   x_bf  = (u16*)(ws);                         //  64 MiB
  u16*   tw    = (u16*)(ws + 67108864);              //  32 MiB
  float* M     = (float*)(ws + 100663296);           //   8 MiB
  float* X     = (float*)(ws + 109051904);           //   8 MiB
  float* T     = (float*)(ws + 117440512);           //   8 MiB
  float* X2    = (float*)(ws + 125829120);           //   8 MiB
  float* alpha = (float*)(ws + 134217728);           //  32 B

  const long long BS2 = 262144;  // 512*512
  dim3 gN(4, 4, 8);

  // M = c0 I + S
  k_build_M<<<dim3(16, 16, 8), 256, 0, stream>>>(R, M);
  // H = M^T M = -M@M + 2c0 M   (into T)
  k_smm<0, 0><<<gN, 256, 0, stream>>>(M, 512, BS2, M, 512, BS2,
                                      T, 512, BS2, M, 512, BS2, 2.0f * C0, -1.f, 512);
  // H2 = H@H (into X) ; H4 = H2@H2 (into X2)
  k_smm<0, 0><<<gN, 256, 0, stream>>>(T, 512, BS2, T, 512, BS2,
                                      X, 512, BS2, T, 512, BS2, 0.f, 1.f, 512);
  k_smm<0, 0><<<gN, 256, 0, stream>>>(X, 512, BS2, X, 512, BS2,
                                      X2, 512, BS2, X, 512, BS2, 0.f, 1.f, 512);
  // alpha[n] from tr(H^8) = ||H4||_F^2
  k_frob_alpha<<<8, 1024, 0, stream>>>(X2, alpha);
  // X0 = alpha * (2c0 I - M)
  k_init_X0<<<8192, 256, 0, stream>>>(M, alpha, X);

  float* Xc = X;
  float* Xn = X2;
  for (int it = 0; it < 6; ++it) {   // bf16 Newton: T = M X ; X <- 2X - X T
    k_smm<0, 0><<<gN, 256, 0, stream>>>(M, 512, BS2, Xc, 512, BS2,
                                        T, 512, BS2, Xc, 512, BS2, 0.f, 1.f, 512);
    k_smm<0, 0><<<gN, 256, 0, stream>>>(Xc, 512, BS2, T, 512, BS2,
                                        Xn, 512, BS2, Xc, 512, BS2, 2.f, -1.f, 512);
    float* tmp = Xc; Xc = Xn; Xn = tmp;
  }
  // split-precision polish iteration
  k_smm<1, 0><<<gN, 256, 0, stream>>>(M, 512, BS2, Xc, 512, BS2,
                                      T, 512, BS2, Xc, 512, BS2, 0.f, 1.f, 512);
  k_smm<1, 0><<<gN, 256, 0, stream>>>(Xc, 512, BS2, T, 512, BS2,
                                      Xn, 512, BS2, Xc, 512, BS2, 2.f, -1.f, 512);
  { float* tmp = Xc; Xc = Xn; Xn = tmp; }
  // Q = (2+1e-6) X - M X   (into T)
  k_smm<1, 0><<<gN, 256, 0, stream>>>(M, 512, BS2, Xc, 512, BS2,
                                      T, 512, BS2, Xc, 512, BS2, C1Q, -1.f, 512);
  // tw = W @ blockdiag(Q), bf16 out
  dim3 gT(4, 32, 8);
  k_smm<0, 1><<<gT, 256, 0, stream>>>(W, 4096, 512, T, 512, BS2,
                                      tw, 4096, 512, W, 4096, 512, 0.f, 1.f, 512);
  // x -> bf16 ; main GEMM
  k_f32_to_bf16<<<16384, 256, 0, stream>>>(x, x_bf);
  k_gemm256<<<dim3(16, 32), 512, 0, stream>>>(x_bf, tw, bias, out, 4096, 4096);
}

// Round 5
// 573.018 us; speedup vs baseline: 5.3320x; 1.8034x over previous
//
#include <hip/hip_runtime.h>
#include <hip/hip_bf16.h>

// EnhancedOFTLinearLayer: out = x @ (W @ blockdiag(cayley(R)))^T + bias
//   cayley(A): S = 0.5(A - A^T); Q = (I - S) @ inv((1+1e-6)I + S)
// Round 4: Newton/Cayley chain rewritten as bf16-native C=A@B^T kernels
// (global_load_lds staging, 64x64 tiles, 512 blocks, granule-XOR swizzle).
// All 512^2 intermediates live in the d_out arena (overwritten by final GEMM).

typedef unsigned short u16;
typedef __attribute__((ext_vector_type(8))) __bf16 bf16x8;
typedef __attribute__((ext_vector_type(4))) float f32x4;
typedef __attribute__((ext_vector_type(8))) unsigned short u16x8;
typedef __attribute__((ext_vector_type(4))) unsigned short u16x4;

#define C0   1.000001f   /* 1 + 1e-6 */
#define C1Q  2.000001f   /* 1 + C0   */
#define AS1 __attribute__((address_space(1)))
#define AS3 __attribute__((address_space(3)))

__device__ __forceinline__ u16 f2bf(float x) {
  union { float f; unsigned u; } v; v.f = x;
  return (u16)((v.u + 0x7fffu + ((v.u >> 16) & 1u)) >> 16);
}
__device__ __forceinline__ float bf2f(u16 h) {
  union { float f; unsigned u; } v; v.u = ((unsigned)h) << 16; return v.f;
}

// ---------------- 1) M = (1+1e-6)I + 0.5(R - R^T) -> bf16 hi/lo pair --------
__global__ __launch_bounds__(256) void k_build_M(const float* __restrict__ R,
                                                 u16* __restrict__ Mh,
                                                 u16* __restrict__ Ml) {
  __shared__ float t1[32][33];
  const int n = blockIdx.z;
  const int tr = blockIdx.y * 32, tc = blockIdx.x * 32;
  const int ly = threadIdx.x >> 5, lx = threadIdx.x & 31;   // 8 x 32
  const float* Rb = R + (size_t)n * 262144;
  float a[4];
#pragma unroll
  for (int i = 0; i < 4; ++i) {
    a[i] = Rb[(size_t)(tr + ly + i * 8) * 512 + tc + lx];
    t1[ly + i * 8][lx] = Rb[(size_t)(tc + ly + i * 8) * 512 + tr + lx];
  }
  __syncthreads();
#pragma unroll
  for (int i = 0; i < 4; ++i) {
    const int r = tr + ly + i * 8, c = tc + lx;
    float m = 0.5f * (a[i] - t1[lx][ly + i * 8]) + (r == c ? C0 : 0.0f);
    u16 h = f2bf(m);
    const size_t idx = (size_t)n * 262144 + (size_t)r * 512 + c;
    Mh[idx] = h;
    Ml[idx] = f2bf(m - bf2f(h));
  }
}

// ---------------- 2b) alpha[n] = 2/(c0^2 + (||G4||_F^2)^(1/8)) --------------
__global__ __launch_bounds__(1024) void k_frob_alpha(const u16* __restrict__ G4,
                                                     float* __restrict__ alpha) {
  __shared__ float red[16];
  const int n = blockIdx.x, tid = threadIdx.x;
  const u16* src = G4 + (size_t)n * 262144;
  float s = 0.f;
  for (int i = tid; i < 32768; i += 1024) {
    u16x8 v = reinterpret_cast<const u16x8*>(src)[i];
#pragma unroll
    for (int e = 0; e < 8; ++e) { float f = bf2f(v[e]); s += f * f; }
  }
  for (int off = 32; off; off >>= 1) s += __shfl_down(s, off, 64);
  if ((tid & 63) == 0) red[tid >> 6] = s;
  __syncthreads();
  if (tid == 0) {
    float t = 0.f;
    for (int q = 0; q < 16; ++q) t += red[q];
    float lam = powf(t, 0.125f);            // >= lambda_max(M^T M)
    alpha[n] = 2.0f / (C0 * C0 + lam);
  }
}

// ---------------- 3a) X0 = alpha*(2c0 I - M) ; X0^T = alpha*M ---------------
__global__ __launch_bounds__(256) void k_init_X0(const u16* __restrict__ Mh,
                                                 const u16* __restrict__ Ml,
                                                 const float* __restrict__ alpha,
                                                 u16* __restrict__ X0,
                                                 u16* __restrict__ X0t) {
  int idx = blockIdx.x * 256 + threadIdx.x;
  int n = idx >> 18, r = (idx >> 9) & 511, c = idx & 511;
  float m = bf2f(Mh[idx]) + bf2f(Ml[idx]);
  float a = alpha[n];
  X0[idx]  = f2bf(a * ((r == c ? 2.0f * C0 : 0.0f) - m));
  X0t[idx] = f2bf(a * m);
}

// ---------------- batched bf16 mm: C = cd*D + cs*(A @ B^T) ------------------
// All matrices [8][512][512] bf16 row-major; B pre-transposed (k-contiguous).
// PROD3: A,B given as hi/lo pairs -> 3-MFMA split product (~fp21).
// DMODE: 0 none, 1 D=Dh, 2 D=Dh+Dl.  OMODE bits: 1 Cnh, 2 Cnl, 4 Cth, 8 Ctl,
// 16 Cf(f32).  Transposed outputs vectorize (4 rows -> one 8B store).
template <int PROD3, int DMODE, int OMODE>
__global__ __launch_bounds__(256)
void k_bmm(const u16* __restrict__ Ah, const u16* __restrict__ Al,
           const u16* __restrict__ Bh, const u16* __restrict__ Bl,
           const u16* __restrict__ Dh, const u16* __restrict__ Dl,
           u16* __restrict__ Cnh, u16* __restrict__ Cnl,
           u16* __restrict__ Cth, u16* __restrict__ Ctl,
           float* __restrict__ Cf, float cd, float cs) {
  __shared__ __align__(16) u16 sAh[2048], sBh[2048];
  __shared__ __align__(16) u16 sAl[PROD3 ? 2048 : 8], sBl[PROD3 ? 2048 : 8];
  const size_t zb = (size_t)blockIdx.z * 262144;
  const int tid = threadIdx.x, lane = tid & 63, wave = tid >> 6;
  const int m0 = blockIdx.y * 64, n0 = blockIdx.x * 64;
  const int wr = wave >> 1, wc = wave & 1;
  const int c15 = lane & 15, lk = lane >> 4;
  const int srow = tid >> 2;
  const int sg = (tid & 3) ^ (srow & 3);            // granule-XOR (involution)
  f32x4 acc[2][2] = {};
  const u16* pa = Ah + zb + (size_t)(m0 + srow) * 512 + sg * 8;
  const u16* pb = Bh + zb + (size_t)(n0 + srow) * 512 + sg * 8;

  for (int k0 = 0; k0 < 512; k0 += 32) {
    __builtin_amdgcn_global_load_lds((const AS1 void*)(pa + k0),
                                     (AS3 void*)(sAh + (size_t)tid * 8), 16, 0, 0);
    __builtin_amdgcn_global_load_lds((const AS1 void*)(pb + k0),
                                     (AS3 void*)(sBh + (size_t)tid * 8), 16, 0, 0);
    if constexpr (PROD3) {
      const u16* pal = Al + zb + (size_t)(m0 + srow) * 512 + sg * 8;
      const u16* pbl = Bl + zb + (size_t)(n0 + srow) * 512 + sg * 8;
      __builtin_amdgcn_global_load_lds((const AS1 void*)(pal + k0),
                                       (AS3 void*)(sAl + (size_t)tid * 8), 16, 0, 0);
      __builtin_amdgcn_global_load_lds((const AS1 void*)(pbl + k0),
                                       (AS3 void*)(sBl + (size_t)tid * 8), 16, 0, 0);
    }
    __syncthreads();
    bf16x8 a[2], b[2], al2[2], bl2[2];
#pragma unroll
    for (int i = 0; i < 2; ++i) {
      const int fr = wr * 32 + i * 16 + c15;
      const int ia = fr * 32 + ((lk ^ (fr & 3)) * 8);
      a[i] = *reinterpret_cast<const bf16x8*>(&sAh[ia]);
      if constexpr (PROD3) al2[i] = *reinterpret_cast<const bf16x8*>(&sAl[ia]);
    }
#pragma unroll
    for (int j = 0; j < 2; ++j) {
      const int fc = wc * 32 + j * 16 + c15;
      const int ib = fc * 32 + ((lk ^ (fc & 3)) * 8);
      b[j] = *reinterpret_cast<const bf16x8*>(&sBh[ib]);
      if constexpr (PROD3) bl2[j] = *reinterpret_cast<const bf16x8*>(&sBl[ib]);
    }
#pragma unroll
    for (int i = 0; i < 2; ++i)
#pragma unroll
      for (int j = 0; j < 2; ++j) {
        acc[i][j] = __builtin_amdgcn_mfma_f32_16x16x32_bf16(a[i], b[j], acc[i][j], 0, 0, 0);
        if constexpr (PROD3) {
          acc[i][j] = __builtin_amdgcn_mfma_f32_16x16x32_bf16(a[i],   bl2[j], acc[i][j], 0, 0, 0);
          acc[i][j] = __builtin_amdgcn_mfma_f32_16x16x32_bf16(al2[i], b[j],   acc[i][j], 0, 0, 0);
        }
      }
    __syncthreads();
  }
  // epilogue (C/D map: col=lane&15, row=(lane>>4)*4+r)
#pragma unroll
  for (int i = 0; i < 2; ++i)
#pragma unroll
    for (int j = 0; j < 2; ++j) {
      const int rowb = m0 + wr * 32 + i * 16 + lk * 4;
      const int col  = n0 + wc * 32 + j * 16 + c15;
      u16 hv[4], lv[4];
#pragma unroll
      for (int r = 0; r < 4; ++r) {
        float val = cs * acc[i][j][r];
        if constexpr (DMODE >= 1) {
          float d = bf2f(Dh[zb + (size_t)(rowb + r) * 512 + col]);
          if constexpr (DMODE == 2) d += bf2f(Dl[zb + (size_t)(rowb + r) * 512 + col]);
          val += cd * d;
        }
        if constexpr (OMODE & 16) Cf[zb + (size_t)(rowb + r) * 512 + col] = val;
        u16 h = f2bf(val);
        if constexpr (OMODE & 1) Cnh[zb + (size_t)(rowb + r) * 512 + col] = h;
        u16 l = 0;
        if constexpr (OMODE & 10) l = f2bf(val - bf2f(h));
        if constexpr (OMODE & 2) Cnl[zb + (size_t)(rowb + r) * 512 + col] = l;
        hv[r] = h; lv[r] = l;
      }
      if constexpr (OMODE & 4) {
        u16x4 v; v[0] = hv[0]; v[1] = hv[1]; v[2] = hv[2]; v[3] = hv[3];
        *reinterpret_cast<u16x4*>(&Cth[zb + (size_t)col * 512 + rowb]) = v;
      }
      if constexpr (OMODE & 8) {
        u16x4 v; v[0] = lv[0]; v[1] = lv[1]; v[2] = lv[2]; v[3] = lv[3];
        *reinterpret_cast<u16x4*>(&Ctl[zb + (size_t)col * 512 + rowb]) = v;
      }
    }
}

// ---------------- tw = W @ blockdiag(Q): f32-in batched mm (proven) ---------
template <int SPLIT, int BF16OUT>
__global__ __launch_bounds__(256)
void k_smm(const float* __restrict__ A, int lda, long long astride,
           const float* __restrict__ B, int ldb, long long bstride,
           void* __restrict__ Cv, int ldc, long long cstride,
           const float* __restrict__ D, int ldd, long long dstride,
           float c1, float sgn, int K) {
  __shared__ __align__(16) u16 lA  [128 * 40];
  __shared__ __align__(16) u16 lBT [128 * 40];
  const int nz = blockIdx.z;
  const float* Ab = A + (size_t)nz * astride;
  const float* Bb = B + (size_t)nz * bstride;
  const float* Db = D + (size_t)nz * dstride;
  const int tid = threadIdx.x, lane = tid & 63, wave = tid >> 6;
  const int m0 = blockIdx.y * 128, n0 = blockIdx.x * 128;
  const int wr = wave >> 1, wc = wave & 1;
  f32x4 acc[4][4] = {};

  for (int k0 = 0; k0 < K; k0 += 32) {
    if (k0) __syncthreads();
    {  // stage A tile [128 x 32]
      const int row = tid >> 1, ks = (tid & 1) * 16;
      const float* src = Ab + (size_t)(m0 + row) * lda + k0 + ks;
      float fv[16];
#pragma unroll
      for (int q = 0; q < 4; ++q) {
        float4 f = *(reinterpret_cast<const float4*>(src) + q);
        fv[q * 4 + 0] = f.x; fv[q * 4 + 1] = f.y; fv[q * 4 + 2] = f.z; fv[q * 4 + 3] = f.w;
      }
      u16x8 w0, w1;
#pragma unroll
      for (int e = 0; e < 8; ++e) { w0[e] = f2bf(fv[e]); w1[e] = f2bf(fv[e + 8]); }
      *reinterpret_cast<u16x8*>(&lA[row * 40 + ks])     = w0;
      *reinterpret_cast<u16x8*>(&lA[row * 40 + ks + 8]) = w1;
    }
    {  // stage B tile transposed
      const int kk = tid >> 3, nb = (tid & 7) * 16;
      const float* src = Bb + (size_t)(k0 + kk) * ldb + n0 + nb;
      float fv[16];
#pragma unroll
      for (int q = 0; q < 4; ++q) {
        float4 f = *(reinterpret_cast<const float4*>(src) + q);
        fv[q * 4 + 0] = f.x; fv[q * 4 + 1] = f.y; fv[q * 4 + 2] = f.z; fv[q * 4 + 3] = f.w;
      }
#pragma unroll
      for (int e = 0; e < 16; ++e) lBT[(nb + e) * 40 + kk] = f2bf(fv[e]);
    }
    __syncthreads();
    const int ks = (lane >> 4) * 8;
    bf16x8 af[4], bfr[4];
#pragma unroll
    for (int f = 0; f < 4; ++f) {
      const int ar = wr * 64 + f * 16 + (lane & 15);
      const int bc = wc * 64 + f * 16 + (lane & 15);
      af[f]  = *reinterpret_cast<const bf16x8*>(&lA [ar * 40 + ks]);
      bfr[f] = *reinterpret_cast<const bf16x8*>(&lBT[bc * 40 + ks]);
    }
#pragma unroll
    for (int i = 0; i < 4; ++i)
#pragma unroll
      for (int j = 0; j < 4; ++j)
        acc[i][j] = __builtin_amdgcn_mfma_f32_16x16x32_bf16(af[i], bfr[j], acc[i][j], 0, 0, 0);
  }
#pragma unroll
  for (int i = 0; i < 4; ++i) {
    const int rowb = m0 + wr * 64 + i * 16 + ((lane >> 4) << 2);
#pragma unroll
    for (int j = 0; j < 4; ++j) {
      const int col = n0 + wc * 64 + j * 16 + (lane & 15);
#pragma unroll
      for (int r = 0; r < 4; ++r) {
        float val = sgn * acc[i][j][r];
        if (c1 != 0.0f) val += c1 * Db[(size_t)(rowb + r) * ldd + col];
        if constexpr (BF16OUT)
          reinterpret_cast<u16*>(Cv)[(size_t)nz * cstride + (size_t)(rowb + r) * ldc + col] = f2bf(val);
        else
          reinterpret_cast<float*>(Cv)[(size_t)nz * cstride + (size_t)(rowb + r) * ldc + col] = val;
      }
    }
  }
}

// ---------------- 5a) x (f32) -> bf16 ----------------
__global__ __launch_bounds__(256) void k_f32_to_bf16(const float* __restrict__ in,
                                                     u16* __restrict__ out) {
  int idx = blockIdx.x * 256 + threadIdx.x;
  const float* src = in + (size_t)idx * 8;
  float4 f0 = *reinterpret_cast<const float4*>(src);
  float4 f1 = *reinterpret_cast<const float4*>(src + 4);
  u16x8 w;
  w[0] = f2bf(f0.x); w[1] = f2bf(f0.y); w[2] = f2bf(f0.z); w[3] = f2bf(f0.w);
  w[4] = f2bf(f1.x); w[5] = f2bf(f1.y); w[6] = f2bf(f1.z); w[7] = f2bf(f1.w);
  *reinterpret_cast<u16x8*>(out + (size_t)idx * 8) = w;
}

// ---------------- 5b) out = x_bf @ tw^T + bias (256^2 4-phase, proven) ------
#define NSLOT 9

#define PHASE(KH, MH, WM)                                                      \
  {                                                                            \
    const int gsk = gs0 ^ ((KH) ? 4 : 0);                                      \
    if ((MH) == 0) {                                                           \
      _Pragma("unroll")                                                        \
      for (int n = 0; n < 4; ++n)                                              \
        bf[n] = *reinterpret_cast<const bf16x8*>(                              \
            &lds[bslot * 8192 + (bro + n * 16) * 64 + gsk * 8]);               \
    }                                                                          \
    _Pragma("unroll")                                                          \
    for (int m = 0; m < 4; ++m)                                                \
      af[m] = *reinterpret_cast<const bf16x8*>(                                \
          &lds[aslot * 8192 + ((MH) * 64 + m * 16 + c15) * 64 + gsk * 8]);     \
    STAGE();                                                                   \
    __builtin_amdgcn_s_barrier();                                              \
    asm volatile("s_waitcnt lgkmcnt(0)" ::: "memory");                         \
    __builtin_amdgcn_sched_barrier(0);                                         \
    __builtin_amdgcn_s_setprio(1);                                             \
    _Pragma("unroll")                                                          \
    for (int m = 0; m < 4; ++m)                                                \
      _Pragma("unroll")                                                        \
      for (int n = 0; n < 4; ++n)                                              \
        acc[(MH) * 4 + m][n] = __builtin_amdgcn_mfma_f32_16x16x32_bf16(        \
            af[m], bf[n], acc[(MH) * 4 + m][n], 0, 0, 0);                      \
    __builtin_amdgcn_s_setprio(0);                                             \
    __builtin_amdgcn_sched_barrier(0);                                         \
    if ((WM) == 1) asm volatile("s_waitcnt vmcnt(2)" ::: "memory");            \
    if ((WM) == 2) asm volatile("s_waitcnt vmcnt(0)" ::: "memory");            \
    __builtin_amdgcn_s_barrier();                                              \
  }

#define ADV()                                                                  \
  aslot += 4; if (aslot >= NSLOT) aslot -= NSLOT;                              \
  bslot += 4; if (bslot >= NSLOT) bslot -= NSLOT;

__global__ __launch_bounds__(512, 2)
void k_gemm256(const u16* __restrict__ A, const u16* __restrict__ B,
               const float* __restrict__ bias,
               float* __restrict__ C, int N, int K) {
  __shared__ __align__(16) u16 lds[NSLOT * 8192];   // 144 KiB
  const int tid = threadIdx.x, lane = tid & 63, wave = tid >> 6;
  int bid = blockIdx.y * gridDim.x + blockIdx.x;
  const int cpx = (gridDim.x * gridDim.y) >> 3;
  bid = (bid & 7) * cpx + (bid >> 3);
  const int nbx = N >> 8;
  const int bx = bid % nbx, by = bid / nbx;
  const int m0 = by << 8, n0 = bx << 8;
  const int wr = wave >> 2, wc = wave & 3;
  const int srow = tid >> 3;
  const int scg  = (tid & 7) ^ (srow & 7);
  const int c15 = lane & 15, lq = lane >> 4;
  const int gs0 = lq ^ (lane & 7);
  const int bro = (wc & 1) * 64 + c15;
  const int NT = K >> 6;

  f32x4 acc[8][4] = {};
  bf16x8 af[4], bf[4];

  int jn = 0, jslot = 0;
  auto STAGE = [&]() {
    if (jn < 4 * NT) {
      const int tau_s = jn >> 2, qh = jn & 3;
      const u16* srcb = (qh < 2)
          ? A + (size_t)(m0 + (qh & 1) * 128 + srow) * (size_t)K
          : B + (size_t)(n0 + (qh & 1) * 128 + srow) * (size_t)K;
      const u16* src = srcb + (tau_s << 6) + scg * 8;
      u16* dst = (u16*)lds + jslot * 8192 + wave * 512;
      __builtin_amdgcn_global_load_lds(
          (const AS1 void*)src, (AS3 void*)dst, 16, 0, 0);
      __builtin_amdgcn_global_load_lds(
          (const AS1 void*)(src + (size_t)64 * K), (AS3 void*)(dst + 4096), 16, 0, 0);
    }
    ++jn; jslot = (jslot == NSLOT - 1) ? 0 : jslot + 1;
  };

  STAGE(); STAGE(); STAGE(); STAGE(); STAGE();
  asm volatile("s_waitcnt vmcnt(2)" ::: "memory");
  __builtin_amdgcn_sched_barrier(0);
  __builtin_amdgcn_s_barrier();

  int aslot = wr, bslot = 2 + (wc >> 1);
  for (int tau = 0; tau < NT - 2; ++tau) {
    PHASE(0, 0, 0)
    PHASE(0, 1, 0)
    PHASE(1, 0, 0)
    PHASE(1, 1, 1)
    ADV()
  }
  PHASE(0, 0, 0)
  PHASE(0, 1, 0)
  PHASE(1, 0, 0)
  PHASE(1, 1, 2)
  ADV()
  PHASE(0, 0, 0)
  PHASE(0, 1, 0)
  PHASE(1, 0, 0)
  PHASE(1, 1, 0)

#pragma unroll
  for (int n = 0; n < 4; ++n) {
    const int col = n0 + wc * 64 + n * 16 + c15;
    const float bv = bias[col];
#pragma unroll
    for (int mi = 0; mi < 8; ++mi) {
      const int rowb = m0 + wr * 128 + mi * 16 + (lq << 2);
#pragma unroll
      for (int r = 0; r < 4; ++r)
        C[(size_t)(rowb + r) * N + col] = acc[mi][n][r] + bv;
    }
  }
}

extern "C" void kernel_launch(void* const* d_in, const int* in_sizes, int n_in,
                              void* d_out, int out_size, void* d_ws, size_t ws_size,
                              hipStream_t stream) {
  const float* W    = (const float*)d_in[0];   // [4096,4096]
  const float* bias = (const float*)d_in[1];   // [4096]
  const float* x    = (const float*)d_in[2];   // [4,2048,4096]
  const float* R    = (const float*)d_in[3];   // [8,512,512]
  float* out = (float*)d_out;

  char* ws = (char*)d_ws;
  u16* x_bf = (u16*)(ws);                      //  64 MiB
  u16* tw   = (u16*)(ws + 67108864);           //  32 MiB

  // scratch arena = d_out (128 MiB; fully overwritten by k_gemm256 at the end)
  char* arena = (char*)d_out;
  auto slot = [&](int i) -> u16* { return (u16*)(arena + (size_t)i * 4194304); };
  u16 *Mh = slot(0), *Ml = slot(1);
  u16 *G = slot(2), *G2 = slot(3), *G4 = slot(4);
  u16 *Xa = slot(5), *Xat = slot(6), *Xb = slot(7), *Xbt = slot(8);
  u16 *Xbl = slot(9), *Xbtl = slot(10);
  u16 *Tt = slot(2);                            // reuse G
  u16 *Tth = slot(3), *Ttl = slot(4);           // reuse G2, G4
  u16 *X6h = slot(5), *X6l = slot(6);           // reuse Xa/Xat (dead)
  u16 *X6th = slot(11), *X6tl = slot(12);
  float* Qf = (float*)(arena + (size_t)13 * 4194304);   // 8 MiB (slots 13-14)
  float* alpha = (float*)(arena + (size_t)15 * 4194304);

  const long long BS2 = 262144;
  const dim3 g8(8, 8, 8);
  const u16* NUL = nullptr;

  // 1) M pair
  k_build_M<<<dim3(16, 16, 8), 256, 0, stream>>>(R, Mh, Ml);
  // 2) G = M@M^T ; G2 = G@G^T ; G4 = G2@G2^T ; alpha from tr(G^8)
  k_bmm<0, 0, 1><<<g8, 256, 0, stream>>>(Mh, NUL, Mh, NUL, NUL, NUL,
                                         G, nullptr, nullptr, nullptr, nullptr, 0.f, 1.f);
  k_bmm<0, 0, 1><<<g8, 256, 0, stream>>>(G, NUL, G, NUL, NUL, NUL,
                                         G2, nullptr, nullptr, nullptr, nullptr, 0.f, 1.f);
  k_bmm<0, 0, 1><<<g8, 256, 0, stream>>>(G2, NUL, G2, NUL, NUL, NUL,
                                         G4, nullptr, nullptr, nullptr, nullptr, 0.f, 1.f);
  k_frob_alpha<<<8, 1024, 0, stream>>>(G4, alpha);
  // 3) X0 pair
  k_init_X0<<<8192, 256, 0, stream>>>(Mh, Ml, alpha, Xa, Xat);

  // 4) Newton iters 1-4 (bf16): T^T = (M@X)^T ; X' = 2X - X@T (+X'^T)
  u16 *cur = Xa, *curt = Xat, *nxt = Xb, *nxtt = Xbt;
  for (int it = 0; it < 4; ++it) {
    k_bmm<0, 0, 4><<<g8, 256, 0, stream>>>(Mh, NUL, curt, NUL, NUL, NUL,
                                           nullptr, nullptr, Tt, nullptr, nullptr, 0.f, 1.f);
    k_bmm<0, 1, 5><<<g8, 256, 0, stream>>>(cur, NUL, Tt, NUL, cur, NUL,
                                           nxt, nullptr, nxtt, nullptr, nullptr, 2.f, -1.f);
    u16* t;
    t = cur; cur = nxt; nxt = t;
    t = curt; curt = nxtt; nxtt = t;
  }
  // iter 5: write hi/lo pairs (normal + transposed)   [cur==Xa here]
  k_bmm<0, 0, 4><<<g8, 256, 0, stream>>>(Mh, NUL, curt, NUL, NUL, NUL,
                                         nullptr, nullptr, Tt, nullptr, nullptr, 0.f, 1.f);
  k_bmm<0, 1, 15><<<g8, 256, 0, stream>>>(cur, NUL, Tt, NUL, cur, NUL,
                                          Xb, Xbl, Xbt, Xbtl, nullptr, 2.f, -1.f);
  // 5) split-precision polish: T^T pair ; X6 = 2X5 - X5@T (pairs)
  k_bmm<1, 0, 12><<<g8, 256, 0, stream>>>(Mh, Ml, Xbt, Xbtl, NUL, NUL,
                                          nullptr, nullptr, Tth, Ttl, nullptr, 0.f, 1.f);
  k_bmm<1, 2, 15><<<g8, 256, 0, stream>>>(Xb, Xbl, Tth, Ttl, Xb, Xbl,
                                          X6h, X6l, X6th, X6tl, nullptr, 2.f, -1.f);
  // 6) Q = (2+1e-6)X6 - M@X6  (f32 out for tw)
  k_bmm<1, 2, 16><<<g8, 256, 0, stream>>>(Mh, Ml, X6th, X6tl, X6h, X6l,
                                          nullptr, nullptr, nullptr, nullptr, Qf, C1Q, -1.f);
  // 7) tw = W @ blockdiag(Q)
  k_smm<0, 1><<<dim3(4, 32, 8), 256, 0, stream>>>(W, 4096, 512, Qf, 512, BS2,
                                                  tw, 4096, 512, W, 4096, 512, 0.f, 1.f, 512);
  // 8) x -> bf16 ; main GEMM (overwrites the arena)
  k_f32_to_bf16<<<16384, 256, 0, stream>>>(x, x_bf);
  k_gemm256<<<dim3(16, 32), 512, 0, stream>>>(x_bf, tw, bias, out, 4096, 4096);
}